// Round 5
// baseline (161.220 us; speedup 1.0000x reference)
//
#include <hip/hip_runtime.h>
#include <hip/hip_bf16.h>
#include <cstdint>
#include <cstddef>

// ---------------------------------------------------------------------------
// Biaffine: out[b,x,y,o] = sum_ij in1[b,x,i] w1[i,o,j] in2[b,y,j] + lin terms
// B=32 S=1024 D=256 O=2.
//   prep : cast inputs to bf16, lin1bf (packed bf16), Btail strip (lin2+bias
//          as a K-tail for gemm2), w1 transpose
//   gemm1: T[bx, oj] = in1b @ w1t^T      (16x16x32, BM=64)
//   gemm2: out = T . in2b (+ lin via K-tail MFMA). A in registers, B streamed
//          through a 4-buffer LDS ring with counted vmcnt + raw s_barrier —
//          epilogue stores are NEVER drained at barriers (T3/T4 pattern).
// ---------------------------------------------------------------------------

typedef __bf16 bf16_t;
typedef __bf16 bf16x4 __attribute__((ext_vector_type(4)));
typedef __bf16 bf16x8 __attribute__((ext_vector_type(8)));
typedef float  f32x4  __attribute__((ext_vector_type(4)));
typedef float  f32x16 __attribute__((ext_vector_type(16)));

#define NB   32
#define NS   1024
#define ND   256
#define NM   (NB * NS)
#define NN1  512

__device__ __forceinline__ void gload_lds16(const void* g, void* l) {
  __builtin_amdgcn_global_load_lds(
      (__attribute__((address_space(1))) void*)g,
      (__attribute__((address_space(3))) void*)l, 16, 0, 0);
}

__device__ __forceinline__ unsigned int bfbits(float f) {
  unsigned int u = __builtin_bit_cast(unsigned int, f);
  u += 0x7fffu + ((u >> 16) & 1u);
  return u >> 16;
}
__device__ __forceinline__ bf16_t bf_frombits(unsigned short u) {
  union { unsigned short s; bf16_t b; } v; v.s = u; return v.b;
}

// ---------------------------------------------------------------------------
// prep: in1/in2 -> bf16; lin1 -> lin1bf (packed bf16 pair per x-row);
// lin2+bias -> Btail[y][16] bf16 strip {1, l2_0, l2_1, 0...}; w1 -> w1t.
// ---------------------------------------------------------------------------
__global__ __launch_bounds__(256) void prep_kernel(
    const float* __restrict__ in1, const float* __restrict__ in2,
    const float* __restrict__ w1,  const float* __restrict__ w2,
    bf16_t* __restrict__ in1b, bf16_t* __restrict__ in2b,
    bf16_t* __restrict__ w1t,  unsigned int* __restrict__ lin1bf,
    bf16_t* __restrict__ btail)
{
  int bid = blockIdx.x;
  if (bid < 16384) {
    int wave = threadIdx.x >> 6;
    int lane = threadIdx.x & 63;
    int r  = bid * 4 + wave;
    int is2 = (r >= NM) ? 1 : 0;
    int lr = r & (NM - 1);
    const float* src = is2 ? in2 : in1;
    bf16_t*      dst = is2 ? in2b : in1b;

    float4 v = *(const float4*)(src + (size_t)lr * ND + lane * 4);
    bf16x4 h;
    h[0] = (bf16_t)v.x; h[1] = (bf16_t)v.y; h[2] = (bf16_t)v.z; h[3] = (bf16_t)v.w;
    *(bf16x4*)(dst + (size_t)lr * ND + lane * 4) = h;

    int dbase = is2 * ND + lane * 4;
    float a0 = v.x * w2[(dbase + 0) * 2 + 0] + v.y * w2[(dbase + 1) * 2 + 0]
             + v.z * w2[(dbase + 2) * 2 + 0] + v.w * w2[(dbase + 3) * 2 + 0];
    float a1 = v.x * w2[(dbase + 0) * 2 + 1] + v.y * w2[(dbase + 1) * 2 + 1]
             + v.z * w2[(dbase + 2) * 2 + 1] + v.w * w2[(dbase + 3) * 2 + 1];
    #pragma unroll
    for (int off = 32; off > 0; off >>= 1) {
      a0 += __shfl_down(a0, off, 64);
      a1 += __shfl_down(a1, off, 64);
    }
    if (lane == 0) {
      if (is2) {
        a0 += w2[2 * ND * 2 + 0]; a1 += w2[2 * ND * 2 + 1];  // bias
        // Btail strip: {1.0, l2_0, l2_1, 0 x13}
        unsigned int w0 = 0x3F80u | (bfbits(a0) << 16);
        unsigned int w1v = bfbits(a1);
        uint4* p = (uint4*)(btail + (size_t)lr * 16);
        uint4 z0; z0.x = w0; z0.y = w1v; z0.z = 0u; z0.w = 0u;
        uint4 z1; z1.x = 0u; z1.y = 0u; z1.z = 0u; z1.w = 0u;
        p[0] = z0; p[1] = z1;
      } else {
        lin1bf[lr] = bfbits(a0) | (bfbits(a1) << 16);
      }
    }
  } else {
    int wb = bid - 16384;
    int t  = threadIdx.x;
    #pragma unroll
    for (int e = 0; e < 8; ++e) {
      int q  = wb * 2048 + e * 256 + t;
      int oj = q >> 8;
      int i  = q & 255;
      w1t[q] = (bf16_t)w1[i * NN1 + oj];
    }
  }
}

// ---------------------------------------------------------------------------
// gemm1 (unchanged): T[m,oj] = in1b[m,:] . w1t[oj,:]
// ---------------------------------------------------------------------------
__global__ __launch_bounds__(256, 3) void gemm1_kernel(
    const bf16_t* __restrict__ A, const bf16_t* __restrict__ Bt,
    bf16_t* __restrict__ T)
{
  __shared__ __align__(16) bf16_t Ap[64 * 256];
  __shared__ __align__(16) bf16_t Bc[2][128 * 32];

  int m0 = blockIdx.x * 64;
  int t = threadIdx.x, lane = t & 63, wid = t >> 6;
  int wm = (wid >> 1) * 32, wn = (wid & 1) * 64;

  #pragma unroll
  for (int i = 0; i < 8; ++i) {
    int unit = i * 256 + t;
    int row = unit >> 5;
    int c   = unit & 31;
    int cs  = c ^ (row & 7);
    gload_lds16(A + (size_t)(m0 + row) * ND + cs * 8, (char*)Ap + unit * 16);
  }
  #pragma unroll
  for (int i = 0; i < 2; ++i) {
    int unit = i * 256 + t;
    int row = unit >> 2, c = unit & 3, cs = c ^ (row & 3);
    gload_lds16(Bt + (size_t)row * ND + cs * 8, (char*)Bc[0] + unit * 16);
  }
  __syncthreads();

  f32x4 acc[2][4] = {};

  for (int s = 0; s < 32; ++s) {
    if (s + 1 < 32) {
      int nt = (s + 1) >> 3, j0 = ((s + 1) & 7) * 32;
      bf16_t* dst = (bf16_t*)Bc[(s + 1) & 1];
      #pragma unroll
      for (int i = 0; i < 2; ++i) {
        int unit = i * 256 + t;
        int row = unit >> 2, c = unit & 3, cs = c ^ (row & 3);
        gload_lds16(Bt + (size_t)(nt * 128 + row) * ND + j0 + cs * 8,
                    (char*)dst + unit * 16);
      }
    }
    const bf16_t* Bcur = Bc[s & 1];
    bf16x8 bfr[4];
    #pragma unroll
    for (int ni = 0; ni < 4; ++ni) {
      int r = wn + ni * 16 + (lane & 15);
      int cp = (lane >> 4) ^ (r & 3);
      bfr[ni] = *(const bf16x8*)&Bcur[r * 32 + cp * 8];
    }
    #pragma unroll
    for (int mi = 0; mi < 2; ++mi) {
      int r = wm + mi * 16 + (lane & 15);
      int cl = (s & 7) * 4 + (lane >> 4);
      int cp = cl ^ (r & 7);
      bf16x8 af = *(const bf16x8*)&Ap[r * 256 + cp * 8];
      #pragma unroll
      for (int ni = 0; ni < 4; ++ni)
        acc[mi][ni] = __builtin_amdgcn_mfma_f32_16x16x32_bf16(
            af, bfr[ni], acc[mi][ni], 0, 0, 0);
    }
    if ((s & 7) == 7) {
      int nt = s >> 3;
      #pragma unroll
      for (int mi = 0; mi < 2; ++mi) {
        int row = m0 + wm + mi * 16 + ((lane >> 4) << 2);
        #pragma unroll
        for (int ni = 0; ni < 4; ++ni) {
          int col = nt * 128 + wn + ni * 16 + (lane & 15);
          #pragma unroll
          for (int r_ = 0; r_ < 4; ++r_)
            T[(size_t)(row + r_) * NN1 + col] = (bf16_t)acc[mi][ni][r_];
          acc[mi][ni] = (f32x4){0.f, 0.f, 0.f, 0.f};
        }
      }
    }
    __syncthreads();
  }
}

// ---------------------------------------------------------------------------
// gemm2: A (64x512) in registers; B via 4-buffer LDS ring (16 KB each, ring
// index = kc compile-time), depth-2 prefetch, counted vmcnt + raw s_barrier.
// lin terms folded as K-tail MFMA (af_t x Btail). 72 KB LDS, 2 blocks/CU.
// ---------------------------------------------------------------------------
__global__ __launch_bounds__(256, 2) void gemm2_kernel(
    const bf16_t* __restrict__ Tm, const bf16_t* __restrict__ in2b,
    const unsigned int* __restrict__ lin1bf, const bf16_t* __restrict__ btail,
    float* __restrict__ out)
{
  __shared__ __align__(16) char smem_all[73728];   // 64K ring (union A) + 2x4K tail
  char* smem    = smem_all;
  char* tailmem = smem_all + 65536;

  // XCD-aware bijective swizzle: 512 blocks, 64/XCD -> 4 batches per XCD
  int blk = (blockIdx.x & 7) * 64 + (blockIdx.x >> 3);
  int b   = blk >> 4;
  int x0  = (blk & 15) * 64;
  const bf16_t* Tb  = Tm    + (size_t)b * NS * NN1;
  const bf16_t* Ib  = in2b  + (size_t)b * NS * ND;
  const bf16_t* Btg = btail + (size_t)b * NS * 16;

  int t = threadIdx.x, lane = t & 63, wid = t >> 6;
  int wx = (wid >> 1) * 32;
  int wy = (wid & 1) * 64;
  int l31 = lane & 31, lhi = lane >> 5;

  // ---- stage A-panel (swizzled) into smem (one-shot, union with ring) ----
  bf16_t* Ap = (bf16_t*)smem;
  #pragma unroll
  for (int i = 0; i < 16; ++i) {
    int unit = i * 256 + t;
    int row = unit >> 6;
    int c   = unit & 63;
    int cs  = c ^ (row & 7);
    gload_lds16(Tb + (size_t)(x0 + row) * NN1 + cs * 8, (char*)Ap + unit * 16);
  }
  __syncthreads();

  // ---- prefill A-frags: af[o][ks] (128 VGPR) ----
  bf16x8 af[2][16];
  {
    int row = wx + l31;
    #pragma unroll
    for (int o = 0; o < 2; ++o)
      #pragma unroll
      for (int ks = 0; ks < 16; ++ks) {
        int ls = o * 32 + ks * 2 + lhi;
        int sm = ls ^ (row & 7);
        af[o][ks] = *(const bf16x8*)&Ap[(row * 64 + sm) * 8];
      }
  }
  __syncthreads();   // Ap dead; ring may overwrite

  // ---- lin1 K-tail frags: af_t[o] = {l1_o, o==0, o==1, 0...} (lhi==0) ----
  unsigned int lv = lin1bf[(size_t)b * NS + x0 + wx + l31];
  bf16x8 aft0 = {}, aft1 = {};
  if (lhi == 0) {
    aft0[0] = bf_frombits((unsigned short)(lv & 0xffffu));
    aft0[1] = bf_frombits(0x3F80u);
    aft1[0] = bf_frombits((unsigned short)(lv >> 16));
    aft1[2] = bf_frombits(0x3F80u);
  }

  f32x16 acc[2][2] = {};   // [ni][o]
  float2* outb = (float2*)(out + (size_t)b * NS * NS * 2);
  int xr = x0 + wx + 4 * lhi;

#define G2_ISSUE(YI2, KC2) do {                                               \
    char* dst_ = smem + (KC2) * 16384;                                        \
    _Pragma("unroll")                                                         \
    for (int i_ = 0; i_ < 4; ++i_) {                                          \
      int u_ = i_ * 256 + t;                                                  \
      int row_ = u_ >> 3, sm_ = u_ & 7;                                       \
      int cs_ = sm_ ^ (row_ & 7);                                             \
      gload_lds16(Ib + (size_t)((YI2) * 128 + row_) * ND + (KC2) * 64 + cs_ * 8, \
                  dst_ + u_ * 16);                                            \
    }                                                                         \
    if ((KC2) == 3) {                                                         \
      char* td_ = tailmem + ((YI2) & 1) * 4096;                               \
      int row_ = t >> 1, h_ = t & 1;                                          \
      gload_lds16(Btg + (size_t)((YI2) * 128 + row_) * 16 + h_ * 8,           \
                  td_ + t * 16);                                              \
    }                                                                         \
  } while (0)

#define G2_STEP(YI, KC, WN, DO_ISSUE) do {                                    \
    if (DO_ISSUE) G2_ISSUE((YI) + ((KC) >= 2 ? 1 : 0), ((KC) + 2) & 3);       \
    asm volatile("s_waitcnt vmcnt(" #WN ")" ::: "memory");                    \
    __builtin_amdgcn_sched_barrier(0);                                        \
    __builtin_amdgcn_s_barrier();                                             \
    __builtin_amdgcn_sched_barrier(0);                                        \
    const bf16_t* Bp_ = (const bf16_t*)(smem + (KC) * 16384);                 \
    _Pragma("unroll")                                                         \
    for (int ni_ = 0; ni_ < 2; ++ni_) {                                       \
      int row_ = wy + ni_ * 32 + l31;                                         \
      _Pragma("unroll")                                                       \
      for (int k2_ = 0; k2_ < 4; ++k2_) {                                     \
        int ls_ = k2_ * 2 + lhi;                                              \
        int sm_ = ls_ ^ (row_ & 7);                                           \
        bf16x8 bf_ = *(const bf16x8*)&Bp_[(row_ * 8 + sm_) * 8];              \
        acc[ni_][0] = __builtin_amdgcn_mfma_f32_32x32x16_bf16(                \
            af[0][(KC) * 4 + k2_], bf_, acc[ni_][0], 0, 0, 0);                \
        acc[ni_][1] = __builtin_amdgcn_mfma_f32_32x32x16_bf16(                \
            af[1][(KC) * 4 + k2_], bf_, acc[ni_][1], 0, 0, 0);                \
      }                                                                       \
    }                                                                         \
    if ((KC) == 3) {                                                          \
      const bf16_t* Tp_ = (const bf16_t*)(tailmem + ((YI) & 1) * 4096);       \
      _Pragma("unroll")                                                       \
      for (int ni_ = 0; ni_ < 2; ++ni_) {                                     \
        int row_ = wy + ni_ * 32 + l31;                                       \
        bf16x8 bt_ = *(const bf16x8*)&Tp_[row_ * 16 + lhi * 8];               \
        acc[ni_][0] = __builtin_amdgcn_mfma_f32_32x32x16_bf16(                \
            aft0, bt_, acc[ni_][0], 0, 0, 0);                                 \
        acc[ni_][1] = __builtin_amdgcn_mfma_f32_32x32x16_bf16(                \
            aft1, bt_, acc[ni_][1], 0, 0, 0);                                 \
      }                                                                       \
      int y0_ = (YI) * 128;                                                   \
      _Pragma("unroll")                                                       \
      for (int r_ = 0; r_ < 16; ++r_) {                                       \
        int row_ = xr + (r_ & 3) + 8 * (r_ >> 2);                             \
        _Pragma("unroll")                                                     \
        for (int ni_ = 0; ni_ < 2; ++ni_) {                                   \
          int col_ = y0_ + wy + ni_ * 32 + l31;                               \
          float2 v_; v_.x = acc[ni_][0][r_]; v_.y = acc[ni_][1][r_];          \
          outb[(size_t)row_ * NS + col_] = v_;                                \
        }                                                                     \
      }                                                                       \
      acc[0][0] = (f32x16)(0.f); acc[0][1] = (f32x16)(0.f);                   \
      acc[1][0] = (f32x16)(0.f); acc[1][1] = (f32x16)(0.f);                   \
    }                                                                         \
  } while (0)

  // prologue: issue chunks 0, 1
  G2_ISSUE(0, 0);
  G2_ISSUE(0, 1);

  // group 0 (peeled: no stores in flight yet)
  G2_STEP(0, 0, 8, true);
  G2_STEP(0, 1, 9, true);
  G2_STEP(0, 2, 9, true);
  G2_STEP(0, 3, 8, true);
  // steady groups
  for (int yi = 1; yi < 7; ++yi) {
    G2_STEP(yi, 0, 40, true);
    G2_STEP(yi, 1, 41, true);
    G2_STEP(yi, 2, 9, true);
    G2_STEP(yi, 3, 8, true);
  }
  // last group (no further issues)
  G2_STEP(7, 0, 40, true);
  G2_STEP(7, 1, 41, true);
  G2_STEP(7, 2, 5, false);
  G2_STEP(7, 3, 0, false);

#undef G2_STEP
#undef G2_ISSUE
}

// ---------------------------------------------------------------------------
extern "C" void kernel_launch(void* const* d_in, const int* in_sizes, int n_in,
                              void* d_out, int out_size, void* d_ws, size_t ws_size,
                              hipStream_t stream) {
  const float* in1 = (const float*)d_in[0];
  const float* in2 = (const float*)d_in[1];
  const float* w1  = (const float*)d_in[2];
  const float* w2  = (const float*)d_in[3];
  float* out = (float*)d_out;

  char* ws = (char*)d_ws;
  bf16_t*       in1b   = (bf16_t*)(ws);                                 // 16 MiB
  bf16_t*       in2b   = (bf16_t*)(ws + (16u << 20));                   // 16 MiB
  bf16_t*       w1t    = (bf16_t*)(ws + (32u << 20));                   // 256 KiB
  unsigned int* lin1bf = (unsigned int*)(ws + (32u << 20) + (256u << 10)); // 128 KiB
  bf16_t*       btail  = (bf16_t*)(ws + (32u << 20) + (512u << 10));    // 1 MiB
  bf16_t*       T      = (bf16_t*)(ws + (34u << 20));                   // 32 MiB

  prep_kernel<<<16448, 256, 0, stream>>>(in1, in2, w1, w2, in1b, in2b, w1t,
                                         lin1bf, btail);
  gemm1_kernel<<<512, 256, 0, stream>>>(in1b, w1t, T);
  gemm2_kernel<<<512, 256, 0, stream>>>(T, in2b, lin1bf, btail, out);
}

// Round 6
// 150.136 us; speedup vs baseline: 1.0738x; 1.0738x over previous
//
#include <hip/hip_runtime.h>
#include <hip/hip_bf16.h>
#include <cstdint>
#include <cstddef>

// ---------------------------------------------------------------------------
// Biaffine: out[b,x,y,o] = sum_ij in1[b,x,i] w1[i,o,j] in2[b,y,j] + lin terms
// B=32 S=1024 D=256 O=2.
//   prep : cast inputs to bf16, lin terms, w1 transpose          (R4 version)
//   gemm1: T[bx, oj] = in1b @ w1t^T      (16x16x32, BM=64)       (R4 version)
//   gemm2: out = T . in2b + lin. 128 x-rows/block, A in registers,
//          B = full-K 128-y panels (64 KB) double-buffered, 8 steps,
//          EVERY step ends in a 128 KB store epilogue -> the per-step
//          __syncthreads drain is store traffic at full HBM rate (the bound).
// ---------------------------------------------------------------------------

typedef __bf16 bf16_t;
typedef __bf16 bf16x4 __attribute__((ext_vector_type(4)));
typedef __bf16 bf16x8 __attribute__((ext_vector_type(8)));
typedef float  f32x4  __attribute__((ext_vector_type(4)));
typedef float  f32x16 __attribute__((ext_vector_type(16)));

#define NB   32
#define NS   1024
#define ND   256
#define NM   (NB * NS)
#define NN1  512

__device__ __forceinline__ void gload_lds16(const void* g, void* l) {
  __builtin_amdgcn_global_load_lds(
      (__attribute__((address_space(1))) void*)g,
      (__attribute__((address_space(3))) void*)l, 16, 0, 0);
}

// ---------------------------------------------------------------------------
// prep (R4 version)
// ---------------------------------------------------------------------------
__global__ __launch_bounds__(256) void prep_kernel(
    const float* __restrict__ in1, const float* __restrict__ in2,
    const float* __restrict__ w1,  const float* __restrict__ w2,
    bf16_t* __restrict__ in1b, bf16_t* __restrict__ in2b,
    bf16_t* __restrict__ w1t,  float* __restrict__ lin)
{
  int bid = blockIdx.x;
  if (bid < 16384) {
    int wave = threadIdx.x >> 6;
    int lane = threadIdx.x & 63;
    int r  = bid * 4 + wave;
    int is2 = (r >= NM) ? 1 : 0;
    int lr = r & (NM - 1);
    const float* src = is2 ? in2 : in1;
    bf16_t*      dst = is2 ? in2b : in1b;

    float4 v = *(const float4*)(src + (size_t)lr * ND + lane * 4);
    bf16x4 h;
    h[0] = (bf16_t)v.x; h[1] = (bf16_t)v.y; h[2] = (bf16_t)v.z; h[3] = (bf16_t)v.w;
    *(bf16x4*)(dst + (size_t)lr * ND + lane * 4) = h;

    int dbase = is2 * ND + lane * 4;
    float a0 = v.x * w2[(dbase + 0) * 2 + 0] + v.y * w2[(dbase + 1) * 2 + 0]
             + v.z * w2[(dbase + 2) * 2 + 0] + v.w * w2[(dbase + 3) * 2 + 0];
    float a1 = v.x * w2[(dbase + 0) * 2 + 1] + v.y * w2[(dbase + 1) * 2 + 1]
             + v.z * w2[(dbase + 2) * 2 + 1] + v.w * w2[(dbase + 3) * 2 + 1];
    #pragma unroll
    for (int off = 32; off > 0; off >>= 1) {
      a0 += __shfl_down(a0, off, 64);
      a1 += __shfl_down(a1, off, 64);
    }
    if (lane == 0) {
      if (is2) { a0 += w2[2 * ND * 2 + 0]; a1 += w2[2 * ND * 2 + 1]; }
      lin[r * 2 + 0] = a0;
      lin[r * 2 + 1] = a1;
    }
  } else {
    int wb = bid - 16384;
    int t  = threadIdx.x;
    #pragma unroll
    for (int e = 0; e < 8; ++e) {
      int q  = wb * 2048 + e * 256 + t;
      int oj = q >> 8;
      int i  = q & 255;
      w1t[q] = (bf16_t)w1[i * NN1 + oj];
    }
  }
}

// ---------------------------------------------------------------------------
// gemm1 (R4 version): T[m,oj] = in1b[m,:] . w1t[oj,:]
// ---------------------------------------------------------------------------
__global__ __launch_bounds__(256, 3) void gemm1_kernel(
    const bf16_t* __restrict__ A, const bf16_t* __restrict__ Bt,
    bf16_t* __restrict__ T)
{
  __shared__ __align__(16) bf16_t Ap[64 * 256];
  __shared__ __align__(16) bf16_t Bc[2][128 * 32];

  int m0 = blockIdx.x * 64;
  int t = threadIdx.x, lane = t & 63, wid = t >> 6;
  int wm = (wid >> 1) * 32, wn = (wid & 1) * 64;

  #pragma unroll
  for (int i = 0; i < 8; ++i) {
    int unit = i * 256 + t;
    int row = unit >> 5;
    int c   = unit & 31;
    int cs  = c ^ (row & 7);
    gload_lds16(A + (size_t)(m0 + row) * ND + cs * 8, (char*)Ap + unit * 16);
  }
  #pragma unroll
  for (int i = 0; i < 2; ++i) {
    int unit = i * 256 + t;
    int row = unit >> 2, c = unit & 3, cs = c ^ (row & 3);
    gload_lds16(Bt + (size_t)row * ND + cs * 8, (char*)Bc[0] + unit * 16);
  }
  __syncthreads();

  f32x4 acc[2][4] = {};

  for (int s = 0; s < 32; ++s) {
    if (s + 1 < 32) {
      int nt = (s + 1) >> 3, j0 = ((s + 1) & 7) * 32;
      bf16_t* dst = (bf16_t*)Bc[(s + 1) & 1];
      #pragma unroll
      for (int i = 0; i < 2; ++i) {
        int unit = i * 256 + t;
        int row = unit >> 2, c = unit & 3, cs = c ^ (row & 3);
        gload_lds16(Bt + (size_t)(nt * 128 + row) * ND + j0 + cs * 8,
                    (char*)dst + unit * 16);
      }
    }
    const bf16_t* Bcur = Bc[s & 1];
    bf16x8 bfr[4];
    #pragma unroll
    for (int ni = 0; ni < 4; ++ni) {
      int r = wn + ni * 16 + (lane & 15);
      int cp = (lane >> 4) ^ (r & 3);
      bfr[ni] = *(const bf16x8*)&Bcur[r * 32 + cp * 8];
    }
    #pragma unroll
    for (int mi = 0; mi < 2; ++mi) {
      int r = wm + mi * 16 + (lane & 15);
      int cl = (s & 7) * 4 + (lane >> 4);
      int cp = cl ^ (r & 7);
      bf16x8 af = *(const bf16x8*)&Ap[r * 256 + cp * 8];
      #pragma unroll
      for (int ni = 0; ni < 4; ++ni)
        acc[mi][ni] = __builtin_amdgcn_mfma_f32_16x16x32_bf16(
            af, bfr[ni], acc[mi][ni], 0, 0, 0);
    }
    if ((s & 7) == 7) {
      int nt = s >> 3;
      #pragma unroll
      for (int mi = 0; mi < 2; ++mi) {
        int row = m0 + wm + mi * 16 + ((lane >> 4) << 2);
        #pragma unroll
        for (int ni = 0; ni < 4; ++ni) {
          int col = nt * 128 + wn + ni * 16 + (lane & 15);
          #pragma unroll
          for (int r_ = 0; r_ < 4; ++r_)
            T[(size_t)(row + r_) * NN1 + col] = (bf16_t)acc[mi][ni][r_];
          acc[mi][ni] = (f32x4){0.f, 0.f, 0.f, 0.f};
        }
      }
    }
    __syncthreads();
  }
}

// ---------------------------------------------------------------------------
// gemm2: block = (b, 128-row x-tile), 8 waves (512 thr), 1 block/CU.
// A = T[x0:x0+128, 0:512] prefilled to registers (af[2][16] = 128 VGPR/wave;
// each wave owns 32 x-rows). B = in2b[y0:y0+128, 0:256] full-K panels,
// 64 KB each, double-buffered in LDS (union with one-shot A staging).
// 8 steps; each step: issue next panel loads -> 64 MFMA/wave -> epilogue
// stores (128 KB/block) -> __syncthreads (drain = store traffic = roofline).
// ---------------------------------------------------------------------------
__global__ __launch_bounds__(512, 2) void gemm2_kernel(
    const bf16_t* __restrict__ Tm, const bf16_t* __restrict__ in2b,
    const float* __restrict__ lin, float* __restrict__ out)
{
  __shared__ __align__(16) char smem[131072];        // 2 x 64 KB panel ring; A-stage union

  // XCD-aware bijective swizzle: 256 blocks, 32/XCD -> 4 batches per XCD
  int blk = (blockIdx.x & 7) * 32 + (blockIdx.x >> 3);
  int b   = blk >> 3;
  int x0  = (blk & 7) * 128;
  const bf16_t* Tb = Tm   + (size_t)b * NS * NN1;
  const bf16_t* Ib = in2b + (size_t)b * NS * ND;

  int t = threadIdx.x, lane = t & 63, wid = t >> 6;
  int wx = (wid >> 1) * 32;        // x-slot: 0,32,64,96
  int wy = (wid & 1) * 64;         // y-slot within 128-wide y-tile: 0 or 64
  int l31 = lane & 31, lhi = lane >> 5;

  // ---- stage A-panel 128x512 (swizzled) into smem: 8192 16B units ----
  bf16_t* Apan = (bf16_t*)smem;
  #pragma unroll
  for (int i = 0; i < 16; ++i) {
    int unit = i * 512 + t;
    int row = unit >> 6;           // 64 slots/row
    int c   = unit & 63;
    int cs  = c ^ (row & 7);
    gload_lds16(Tb + (size_t)(x0 + row) * NN1 + cs * 8, (char*)Apan + unit * 16);
  }
  __syncthreads();

  // ---- prefill A-frags: af[o][ks] (32 bf16x8 = 128 VGPR) ----
  bf16x8 af[2][16];
  {
    int row = wx + l31;
    #pragma unroll
    for (int o = 0; o < 2; ++o)
      #pragma unroll
      for (int ks = 0; ks < 16; ++ks) {
        int ls = o * 32 + ks * 2 + lhi;
        int sm = ls ^ (row & 7);
        af[o][ks] = *(const bf16x8*)&Apan[(row * 64 + sm) * 8];
      }
  }
  __syncthreads();   // Apan dead; panel ring may overwrite

  // ---- stage B panel 0: rows 0..127, full K=256; 4096 units, 32 slots/row --
  #pragma unroll
  for (int i = 0; i < 8; ++i) {
    int u = i * 512 + t;
    int row = u >> 5, sl = u & 31;
    int cs = sl ^ (row & 7);
    gload_lds16(Ib + (size_t)row * ND + cs * 8, smem + u * 16);
  }
  __syncthreads();

  f32x16 acc[2][2] = {};   // [ni][o]
  float2* outb = (float2*)(out + (size_t)b * NS * NS * 2);
  const float2* l1p = (const float2*)(lin + (size_t)b * NS * 2);
  const float2* l2p = (const float2*)(lin + (size_t)(NM + b * NS) * 2);
  int xr = x0 + wx + 4 * lhi;

  for (int p = 0; p < 8; ++p) {
    // issue next panel's loads into the other slot (holds panel p-1: consumed)
    if (p + 1 < 8) {
      char* dst = smem + ((p + 1) & 1) * 65536;
      #pragma unroll
      for (int i = 0; i < 8; ++i) {
        int u = i * 512 + t;
        int row = u >> 5, sl = u & 31;
        int cs = sl ^ (row & 7);
        gload_lds16(Ib + (size_t)((p + 1) * 128 + row) * ND + cs * 8,
                    dst + u * 16);
      }
    }
    // compute on panel p
    const bf16_t* Bp = (const bf16_t*)(smem + (p & 1) * 65536);
    #pragma unroll
    for (int ks = 0; ks < 16; ++ks) {
      #pragma unroll
      for (int ni = 0; ni < 2; ++ni) {
        int row = wy + ni * 32 + l31;
        int ls = ks * 2 + lhi;
        int sm = ls ^ (row & 7);
        bf16x8 bfv = *(const bf16x8*)&Bp[(row * 32 + sm) * 8];
        acc[ni][0] = __builtin_amdgcn_mfma_f32_32x32x16_bf16(
            af[0][ks], bfv, acc[ni][0], 0, 0, 0);
        acc[ni][1] = __builtin_amdgcn_mfma_f32_32x32x16_bf16(
            af[1][ks], bfv, acc[ni][1], 0, 0, 0);
      }
    }
    // epilogue: y-tile p done -> store 128 rows x 128 cols x float2
    {
      int y0 = p * 128;
      float2 l2[2];
      #pragma unroll
      for (int ni = 0; ni < 2; ++ni) l2[ni] = l2p[y0 + wy + ni * 32 + l31];
      #pragma unroll
      for (int r = 0; r < 16; ++r) {
        int row = xr + (r & 3) + 8 * (r >> 2);
        float2 l1 = l1p[row];
        #pragma unroll
        for (int ni = 0; ni < 2; ++ni) {
          int col = y0 + wy + ni * 32 + l31;
          float2 v;
          v.x = acc[ni][0][r] + l1.x + l2[ni].x;
          v.y = acc[ni][1][r] + l1.y + l2[ni].y;
          outb[(size_t)row * NS + col] = v;
        }
      }
      acc[0][0] = (f32x16)(0.f); acc[0][1] = (f32x16)(0.f);
      acc[1][0] = (f32x16)(0.f); acc[1][1] = (f32x16)(0.f);
    }
    __syncthreads();
  }
}

// ---------------------------------------------------------------------------
extern "C" void kernel_launch(void* const* d_in, const int* in_sizes, int n_in,
                              void* d_out, int out_size, void* d_ws, size_t ws_size,
                              hipStream_t stream) {
  const float* in1 = (const float*)d_in[0];
  const float* in2 = (const float*)d_in[1];
  const float* w1  = (const float*)d_in[2];
  const float* w2  = (const float*)d_in[3];
  float* out = (float*)d_out;

  char* ws = (char*)d_ws;
  bf16_t* in1b = (bf16_t*)(ws);                                   // 16 MiB
  bf16_t* in2b = (bf16_t*)(ws + (16u << 20));                     // 16 MiB
  bf16_t* w1t  = (bf16_t*)(ws + (32u << 20));                     // 256 KiB
  float*  lin  = (float*) (ws + (32u << 20) + (256u << 10));      // 512 KiB
  bf16_t* T    = (bf16_t*)(ws + (33u << 20));                     // 32 MiB

  prep_kernel<<<16448, 256, 0, stream>>>(in1, in2, w1, w2, in1b, in2b, w1t, lin);
  gemm1_kernel<<<512, 256, 0, stream>>>(in1b, w1t, T);
  gemm2_kernel<<<256, 512, 0, stream>>>(T, in2b, lin, out);
}